// Round 1
// baseline (1024.074 us; speedup 1.0000x reference)
//
#include <hip/hip_runtime.h>
#include <math.h>

#define N_NODES 50000
#define N_EDGES 800000
#define T_TOW 5
#define F_DIM 10
#define G_GRAPHS 64

// ---------------- mlp1: h = relu(x@w1+b1)@w2+b2 ----------------
__global__ void k_mlp1(const float* __restrict__ x,
                       const float* __restrict__ w1, const float* __restrict__ b1,
                       const float* __restrict__ w2, const float* __restrict__ b2,
                       float* __restrict__ h) {
  int n = blockIdx.x * blockDim.x + threadIdx.x;
  if (n >= N_NODES) return;
  float xv[10];
#pragma unroll
  for (int k = 0; k < 10; k++) xv[k] = x[n * 10 + k];
  float hid[5];
#pragma unroll
  for (int j = 0; j < 5; j++) {
    float a = b1[j];
#pragma unroll
    for (int k = 0; k < 10; k++) a += xv[k] * w1[k * 5 + j];
    hid[j] = fmaxf(a, 0.f);
  }
#pragma unroll
  for (int f = 0; f < 10; f++) {
    float a = b2[f];
#pragma unroll
    for (int j = 0; j < 5; j++) a += hid[j] * w2[j * 10 + f];
    h[n * 10 + f] = a;
  }
}

// ------- precompute encm[l][a][t][f] = sum_k enc_out[l][a][k]*pre_w[l][t][20+k][f] -------
__global__ void k_setup(const float* __restrict__ edge_emb, // [4][10]
                        const float* __restrict__ enc_w,    // [2][10][10]
                        const float* __restrict__ enc_b,    // [2][10]
                        const float* __restrict__ pre_w,    // [2][5][30][10]
                        float* __restrict__ encm)           // [2][4][5][10]
{
  __shared__ float eo[2][4][10];
  int tid = threadIdx.x;
  for (int i = tid; i < 80; i += 64) {
    int l = i / 40; int a = (i / 10) % 4; int k = i % 10;
    float s = enc_b[l * 10 + k];
    for (int j = 0; j < 10; j++) s += edge_emb[a * 10 + j] * enc_w[(l * 10 + j) * 10 + k];
    eo[l][a][k] = s;
  }
  __syncthreads();
  for (int i = tid; i < 400; i += 64) {
    int l = i / 200; int a = (i / 50) % 4; int t = (i / 10) % 5; int f = i % 10;
    float s = 0.f;
    for (int k = 0; k < 10; k++) s += eo[l][a][k] * pre_w[((l * 5 + t) * 30 + 20 + k) * 10 + f];
    encm[i] = s;
  }
}

// ---------------- degree count ----------------
__global__ void k_count(const int* __restrict__ dst, int* __restrict__ cnt) {
  int e = blockIdx.x * blockDim.x + threadIdx.x;
  if (e < N_EDGES) atomicAdd(&cnt[dst[e]], 1);
}

// ---------------- single-block exclusive scan + avg_log ----------------
__global__ void k_scan(const int* __restrict__ cnt, int* __restrict__ rowptr,
                       float* __restrict__ avg_log) {
  __shared__ int wsum[16];
  __shared__ float wlog[16];
  int tid = threadIdx.x;
  int lane = tid & 63, wid = tid >> 6;
  int carry = 0;
  float logacc = 0.f;
  for (int base = 0; base < N_NODES; base += 1024) {
    int i = base + tid;
    int v = (i < N_NODES) ? cnt[i] : 0;
    if (i < N_NODES) logacc += logf((float)v + 1.0f);
    int x = v;
#pragma unroll
    for (int d = 1; d < 64; d <<= 1) {
      int y = __shfl_up(x, d, 64);
      if (lane >= d) x += y;
    }
    if (lane == 63) wsum[wid] = x;
    __syncthreads();
    if (wid == 0) {
      int t = (lane < 16) ? wsum[lane] : 0;
#pragma unroll
      for (int d = 1; d < 16; d <<= 1) {
        int y = __shfl_up(t, d, 64);
        if (lane >= d) t += y;
      }
      if (lane < 16) wsum[lane] = t;
    }
    __syncthreads();
    int wexcl = (wid > 0) ? wsum[wid - 1] : 0;
    int total = wsum[15];
    if (i < N_NODES) rowptr[i] = carry + wexcl + x - v;
    carry += total;
    __syncthreads();
  }
  if (tid == 0) rowptr[N_NODES] = carry;
  float r = logacc;
#pragma unroll
  for (int d = 32; d >= 1; d >>= 1) r += __shfl_down(r, d, 64);
  if (lane == 0) wlog[wid] = r;
  __syncthreads();
  if (tid == 0) {
    float s = 0.f;
    for (int w = 0; w < 16; w++) s += wlog[w];
    avg_log[0] = s / (float)N_NODES;
  }
}

// ---------------- scatter edges into CSR ----------------
__global__ void k_scatter(const int* __restrict__ src, const int* __restrict__ dst,
                          const int* __restrict__ attr,
                          const int* __restrict__ rowptr, int* __restrict__ fill,
                          int* __restrict__ src_s, int* __restrict__ attr_s) {
  int e = blockIdx.x * blockDim.x + threadIdx.x;
  if (e >= N_EDGES) return;
  int d = dst[e];
  int pos = rowptr[d] + atomicAdd(&fill[d], 1);
  src_s[pos] = src[e];
  attr_s[pos] = attr[e];
}

// ---------------- fused PNA conv: gather + stats + post + lin + BN partials ----------------
__global__ __launch_bounds__(256) void k_conv(
    const float* __restrict__ h,
    const float* __restrict__ pre_w_l,   // [5][30][10]
    const float* __restrict__ pre_b_l,   // [5][10]
    const float* __restrict__ post_w_l,  // [5][130][2]
    const float* __restrict__ post_b_l,  // [5][2]
    const float* __restrict__ lin_w_l,   // [10][10]
    const float* __restrict__ lin_b_l,   // [10]
    const float* __restrict__ encm_l,    // [4][50]
    const int* __restrict__ rowptr,
    const int* __restrict__ src_s,
    const int* __restrict__ attr_s,
    const int* __restrict__ cnt,
    const float* __restrict__ avg_log_p,
    float* __restrict__ o_buf,
    float* __restrict__ bn_acc)          // [20]: sum[10], sumsq[10]
{
  __shared__ float sW[1300];
  __shared__ float sLin[110];
  __shared__ float sPB[10];
  __shared__ float sH[4][10];
  __shared__ float sS[4][10];
  __shared__ float sA[4][200];
  __shared__ float sO[4][10];
  __shared__ float bnS[10], bnQ[10];

  int tid = threadIdx.x;
  int wid = tid >> 6, lane = tid & 63;
  for (int i = tid; i < 1300; i += 256) sW[i] = post_w_l[i];
  for (int i = tid; i < 100; i += 256) sLin[i] = lin_w_l[i];
  if (tid < 10) {
    sLin[100 + tid] = lin_b_l[tid];
    sPB[tid] = post_b_l[tid];
    bnS[tid] = 0.f; bnQ[tid] = 0.f;
  }
  __syncthreads();

  int n = blockIdx.x * 4 + wid;
  if (n < N_NODES) {
    bool act = lane < 50;
    int t = lane / 10; if (t > 4) t = 4;
    int f = lane % 10;
    float wsrc[10];
#pragma unroll
    for (int k = 0; k < 10; k++) wsrc[k] = pre_w_l[(t * 30 + 10 + k) * 10 + f];
    if (lane < 10) sH[wid][lane] = h[(long)n * 10 + lane];
    float base = pre_b_l[t * 10 + f];
#pragma unroll
    for (int k = 0; k < 10; k++) base += sH[wid][k] * pre_w_l[(t * 30 + k) * 10 + f];
    float em0 = encm_l[ 0 + t * 10 + f];
    float em1 = encm_l[50 + t * 10 + f];
    float em2 = encm_l[100 + t * 10 + f];
    float em3 = encm_l[150 + t * 10 + f];

    int rs = rowptr[n], re = rowptr[n + 1];
    float sum = 0.f, sq = 0.f, mn = INFINITY, mx = -INFINITY;
    int sN = 0, aN = 0; float hvN = 0.f;
    if (rs < re) {
      sN = src_s[rs]; aN = attr_s[rs];
      hvN = (lane < 10) ? h[(long)sN * 10 + lane] : 0.f;
    }
    for (int idx = rs; idx < re; ++idx) {
      int aC = aN; float hv = hvN;
      int nx = idx + 1;
      if (nx < re) { sN = src_s[nx]; aN = attr_s[nx]; }
      if (lane < 10) sS[wid][lane] = hv;
      if (nx < re) hvN = (lane < 10) ? h[(long)sN * 10 + lane] : 0.f; // prefetch
      float m = base + (aC == 0 ? em0 : aC == 1 ? em1 : aC == 2 ? em2 : em3);
#pragma unroll
      for (int k = 0; k < 10; k++) m += sS[wid][k] * wsrc[k];
      sum += m; sq += m * m;
      mn = fminf(mn, m); mx = fmaxf(mx, m);
    }

    float degf = (float)cnt[n];
    float d = fmaxf(degf, 1.f);
    float inv = 1.f / d;
    bool has_in = degf > 0.f;
    float mean = sum * inv;
    float var = sq * inv - mean * mean;
    float stdv = sqrtf(fmaxf(var, 0.f) + 1e-5f);
    if (!has_in) { mn = 0.f; mx = 0.f; }
    float avg_log = avg_log_p[0];
    float log_d = logf(d + 1.f);
    float amp = log_d / avg_log;
    float att = avg_log / log_d;
    if (act) {
      sA[wid][t * 40 + f]      = mean;
      sA[wid][t * 40 + 10 + f] = mn;
      sA[wid][t * 40 + 20 + f] = mx;
      sA[wid][t * 40 + 30 + f] = stdv;
    }
    if (lane < 10) {
      int tt = lane >> 1, c = lane & 1;
      const float* w = &sW[tt * 260];
      float o = sPB[lane];
#pragma unroll
      for (int k = 0; k < 10; k++) o += sH[wid][k] * w[k * 2 + c];
#pragma unroll
      for (int k = 0; k < 40; k++) {
        float v = sA[wid][tt * 40 + k];
        o += v * (w[(10 + k) * 2 + c] + amp * w[(50 + k) * 2 + c] + att * w[(90 + k) * 2 + c]);
      }
      sO[wid][lane] = o;
    }
    if (lane < 10) {
      float r = sLin[100 + lane];
#pragma unroll
      for (int j = 0; j < 10; j++) r += sO[wid][j] * sLin[j * 10 + lane];
      o_buf[(long)n * 10 + lane] = r;
      atomicAdd(&bnS[lane], r);
      atomicAdd(&bnQ[lane], r * r);
    }
  }
  __syncthreads();
  if (tid < 10) {
    atomicAdd(&bn_acc[tid], bnS[tid]);
    atomicAdd(&bn_acc[10 + tid], bnQ[tid]);
  }
}

// ---------------- BN (train-mode) + relu ----------------
__global__ void k_bn_apply(const float* __restrict__ o_buf,
                           const float* __restrict__ bn_acc,
                           const float* __restrict__ gamma, const float* __restrict__ beta,
                           float* __restrict__ h) {
  int i = blockIdx.x * blockDim.x + threadIdx.x;
  if (i >= N_NODES * F_DIM) return;
  int f = i % 10;
  float mu = bn_acc[f] * (1.f / N_NODES);
  float var = bn_acc[10 + f] * (1.f / N_NODES) - mu * mu;
  float inv = 1.f / sqrtf(fmaxf(var, 0.f) + 1e-5f);
  float o = (o_buf[i] - mu) * inv * gamma[f] + beta[f];
  h[i] = fmaxf(o, 0.f);
}

// ---------------- global add pool ----------------
__global__ void k_pool(const float* __restrict__ h, const int* __restrict__ batch,
                       float* __restrict__ g) {
  int i = blockIdx.x * blockDim.x + threadIdx.x;
  if (i >= N_NODES * F_DIM) return;
  int n = i / 10, f = i % 10;
  atomicAdd(&g[batch[n] * 10 + f], h[i]);
}

// ---------------- mlp2 ----------------
__global__ void k_mlp2(const float* __restrict__ g,
                       const float* __restrict__ w1, const float* __restrict__ b1,
                       const float* __restrict__ w2, const float* __restrict__ b2,
                       float* __restrict__ out) {
  int b = threadIdx.x;
  if (b >= G_GRAPHS) return;
  float gv[10];
#pragma unroll
  for (int k = 0; k < 10; k++) gv[k] = g[b * 10 + k];
  float acc = b2[0];
#pragma unroll
  for (int j = 0; j < 5; j++) {
    float a = b1[j];
#pragma unroll
    for (int k = 0; k < 10; k++) a += gv[k] * w1[k * 5 + j];
    acc += fmaxf(a, 0.f) * w2[j];
  }
  out[b] = acc;
}

extern "C" void kernel_launch(void* const* d_in, const int* in_sizes, int n_in,
                              void* d_out, int out_size, void* d_ws, size_t ws_size,
                              hipStream_t stream) {
  const float* x        = (const float*)d_in[0];
  const float* edge_emb = (const float*)d_in[1];
  const float* m1w1 = (const float*)d_in[2];
  const float* m1b1 = (const float*)d_in[3];
  const float* m1w2 = (const float*)d_in[4];
  const float* m1b2 = (const float*)d_in[5];
  const float* enc_w = (const float*)d_in[6];
  const float* enc_b = (const float*)d_in[7];
  const float* pre_w = (const float*)d_in[8];
  const float* pre_b = (const float*)d_in[9];
  const float* post_w = (const float*)d_in[10];
  const float* post_b = (const float*)d_in[11];
  const float* lin_w = (const float*)d_in[12];
  const float* lin_b = (const float*)d_in[13];
  const float* bn_g = (const float*)d_in[14];
  const float* bn_b = (const float*)d_in[15];
  const float* m2w1 = (const float*)d_in[16];
  const float* m2b1 = (const float*)d_in[17];
  const float* m2w2 = (const float*)d_in[18];
  const float* m2b2 = (const float*)d_in[19];
  const int* edge_index = (const int*)d_in[20];
  const int* edge_attr  = (const int*)d_in[21];
  const int* batch      = (const int*)d_in[22];
  const int* src  = edge_index;
  const int* dstp = edge_index + N_EDGES;

  char* ws = (char*)d_ws;
  size_t off = 0;
  auto alloc = [&](size_t bytes) {
    void* p = ws + off;
    off += (bytes + 255) & ~(size_t)255;
    return p;
  };
  float* h       = (float*)alloc(N_NODES * 10 * sizeof(float));
  float* o_buf   = (float*)alloc(N_NODES * 10 * sizeof(float));
  int*   cnt     = (int*)alloc(N_NODES * sizeof(int));
  int*   fill    = (int*)alloc(N_NODES * sizeof(int));
  int*   rowptr  = (int*)alloc((N_NODES + 1) * sizeof(int));
  int*   src_s   = (int*)alloc(N_EDGES * sizeof(int));
  int*   attr_s  = (int*)alloc(N_EDGES * sizeof(int));
  float* encm    = (float*)alloc(400 * sizeof(float));
  float* avg_log = (float*)alloc(16);
  float* bn_acc  = (float*)alloc(40 * sizeof(float));
  float* g       = (float*)alloc(G_GRAPHS * 10 * sizeof(float));

  hipMemsetAsync(cnt, 0, N_NODES * sizeof(int), stream);
  hipMemsetAsync(fill, 0, N_NODES * sizeof(int), stream);
  hipMemsetAsync(bn_acc, 0, 40 * sizeof(float), stream);
  hipMemsetAsync(g, 0, G_GRAPHS * 10 * sizeof(float), stream);

  k_mlp1<<<(N_NODES + 255) / 256, 256, 0, stream>>>(x, m1w1, m1b1, m1w2, m1b2, h);
  k_setup<<<1, 64, 0, stream>>>(edge_emb, enc_w, enc_b, pre_w, encm);
  k_count<<<(N_EDGES + 255) / 256, 256, 0, stream>>>(dstp, cnt);
  k_scan<<<1, 1024, 0, stream>>>(cnt, rowptr, avg_log);
  k_scatter<<<(N_EDGES + 255) / 256, 256, 0, stream>>>(src, dstp, edge_attr, rowptr, fill,
                                                       src_s, attr_s);

  for (int l = 0; l < 2; l++) {
    k_conv<<<(N_NODES + 3) / 4, 256, 0, stream>>>(
        h, pre_w + l * 1500, pre_b + l * 50, post_w + l * 1300, post_b + l * 10,
        lin_w + l * 100, lin_b + l * 10, encm + l * 200,
        rowptr, src_s, attr_s, cnt, avg_log, o_buf, bn_acc + l * 20);
    k_bn_apply<<<(N_NODES * 10 + 255) / 256, 256, 0, stream>>>(
        o_buf, bn_acc + l * 20, bn_g + l * 10, bn_b + l * 10, h);
  }
  k_pool<<<(N_NODES * 10 + 255) / 256, 256, 0, stream>>>(h, batch, g);
  k_mlp2<<<1, 64, 0, stream>>>(g, m2w1, m2b1, m2w2, m2b2, (float*)d_out);
}

// Round 2
// 1011.620 us; speedup vs baseline: 1.0123x; 1.0123x over previous
//
#include <hip/hip_runtime.h>
#include <math.h>

#define N_NODES 50000
#define N_EDGES 800000
#define G_GRAPHS 64

// ---------------- mlp1 (+ workspace zeroing): h = relu(x@w1+b1)@w2+b2 ----------------
__global__ void k_mlp1(const float* __restrict__ x,
                       const float* __restrict__ w1, const float* __restrict__ b1,
                       const float* __restrict__ w2, const float* __restrict__ b2,
                       float* __restrict__ h,
                       int* __restrict__ cnt, int* __restrict__ fill,
                       float* __restrict__ bn_acc, float* __restrict__ g) {
  int n = blockIdx.x * blockDim.x + threadIdx.x;
  if (n < 40) bn_acc[n] = 0.f;
  if (n < G_GRAPHS * 10) g[n] = 0.f;
  if (n >= N_NODES) return;
  cnt[n] = 0;
  fill[n] = 0;
  float xv[10];
#pragma unroll
  for (int k = 0; k < 10; k++) xv[k] = x[n * 10 + k];
  float hid[5];
#pragma unroll
  for (int j = 0; j < 5; j++) {
    float a = b1[j];
#pragma unroll
    for (int k = 0; k < 10; k++) a += xv[k] * w1[k * 5 + j];
    hid[j] = fmaxf(a, 0.f);
  }
#pragma unroll
  for (int f = 0; f < 10; f++) {
    float a = b2[f];
#pragma unroll
    for (int j = 0; j < 5; j++) a += hid[j] * w2[j * 10 + f];
    h[n * 10 + f] = a;
  }
}

// ------- precompute encm[l][a][t][f] = sum_k enc_out[l][a][k]*pre_w[l][t][20+k][f] -------
__global__ void k_setup(const float* __restrict__ edge_emb, // [4][10]
                        const float* __restrict__ enc_w,    // [2][10][10]
                        const float* __restrict__ enc_b,    // [2][10]
                        const float* __restrict__ pre_w,    // [2][5][30][10]
                        float* __restrict__ encm)           // [2][4][5][10]
{
  __shared__ float eo[2][4][10];
  int tid = threadIdx.x;
  for (int i = tid; i < 80; i += 64) {
    int l = i / 40; int a = (i / 10) % 4; int k = i % 10;
    float s = enc_b[l * 10 + k];
    for (int j = 0; j < 10; j++) s += edge_emb[a * 10 + j] * enc_w[(l * 10 + j) * 10 + k];
    eo[l][a][k] = s;
  }
  __syncthreads();
  for (int i = tid; i < 400; i += 64) {
    int l = i / 200; int a = (i / 50) % 4; int t = (i / 10) % 5; int f = i % 10;
    float s = 0.f;
    for (int k = 0; k < 10; k++) s += eo[l][a][k] * pre_w[((l * 5 + t) * 30 + 20 + k) * 10 + f];
    encm[i] = s;
  }
}

// ---------------- degree count ----------------
__global__ void k_count(const int* __restrict__ dst, int* __restrict__ cnt) {
  int e = blockIdx.x * blockDim.x + threadIdx.x;
  if (e < N_EDGES) atomicAdd(&cnt[dst[e]], 1);
}

// ---------------- single-block exclusive scan + avg_log ----------------
__global__ void k_scan(const int* __restrict__ cnt, int* __restrict__ rowptr,
                       float* __restrict__ avg_log) {
  __shared__ int wsum[16];
  __shared__ float wlog[16];
  int tid = threadIdx.x;
  int lane = tid & 63, wid = tid >> 6;
  int carry = 0;
  float logacc = 0.f;
  for (int base = 0; base < N_NODES; base += 1024) {
    int i = base + tid;
    int v = (i < N_NODES) ? cnt[i] : 0;
    if (i < N_NODES) logacc += logf((float)v + 1.0f);
    int x = v;
#pragma unroll
    for (int d = 1; d < 64; d <<= 1) {
      int y = __shfl_up(x, d, 64);
      if (lane >= d) x += y;
    }
    if (lane == 63) wsum[wid] = x;
    __syncthreads();
    if (wid == 0) {
      int t = (lane < 16) ? wsum[lane] : 0;
#pragma unroll
      for (int d = 1; d < 16; d <<= 1) {
        int y = __shfl_up(t, d, 64);
        if (lane >= d) t += y;
      }
      if (lane < 16) wsum[lane] = t;
    }
    __syncthreads();
    int wexcl = (wid > 0) ? wsum[wid - 1] : 0;
    int total = wsum[15];
    if (i < N_NODES) rowptr[i] = carry + wexcl + x - v;
    carry += total;
    __syncthreads();
  }
  if (tid == 0) rowptr[N_NODES] = carry;
  float r = logacc;
#pragma unroll
  for (int d = 32; d >= 1; d >>= 1) r += __shfl_down(r, d, 64);
  if (lane == 0) wlog[wid] = r;
  __syncthreads();
  if (tid == 0) {
    float s = 0.f;
    for (int w = 0; w < 16; w++) s += wlog[w];
    avg_log[0] = s / (float)N_NODES;
  }
}

// ---------------- scatter edges into CSR ----------------
__global__ void k_scatter(const int* __restrict__ src, const int* __restrict__ dst,
                          const int* __restrict__ attr,
                          const int* __restrict__ rowptr, int* __restrict__ fill,
                          int* __restrict__ src_s, int* __restrict__ attr_s) {
  int e = blockIdx.x * blockDim.x + threadIdx.x;
  if (e >= N_EDGES) return;
  int d = dst[e];
  int pos = rowptr[d] + atomicAdd(&fill[d], 1);
  src_s[pos] = src[e];
  attr_s[pos] = attr[e];
}

#define WAVE_SYNC() asm volatile("s_waitcnt lgkmcnt(0)" ::: "memory")

// ---- fused PNA conv: 6-edge-batched gather + stats + post + lin + BN partials ----
__global__ __launch_bounds__(256) void k_conv(
    const float* __restrict__ h,
    const float* __restrict__ pre_w_l,   // [5][30][10]
    const float* __restrict__ pre_b_l,   // [5][10]
    const float* __restrict__ post_w_l,  // [5][130][2]
    const float* __restrict__ post_b_l,  // [5][2]
    const float* __restrict__ lin_w_l,   // [10][10]
    const float* __restrict__ lin_b_l,   // [10]
    const float* __restrict__ encm_l,    // [4][5][10]
    const int* __restrict__ rowptr,
    const int* __restrict__ src_s,
    const int* __restrict__ attr_s,
    const float* __restrict__ avg_log_p,
    float* __restrict__ o_buf,
    float* __restrict__ bn_acc)          // [20]: sum[10], sumsq[10]
{
  __shared__ float sW[1300];
  __shared__ float sLin[100];
  __shared__ float sLb[10];
  __shared__ float sPb[10];
  __shared__ float sE[4][6][12];   // 6 staged h[src] vectors, padded to 12 (16B aligned)
  __shared__ float sP[4][100];     // post partials [t*10+f] x {c0,c1}
  __shared__ float sO[4][10];
  __shared__ float sHx[4][10];
  __shared__ float bnS[10], bnQ[10];

  int tid = threadIdx.x;
  int wid = tid >> 6, lane = tid & 63;
  for (int i = tid; i < 1300; i += 256) sW[i] = post_w_l[i];
  for (int i = tid; i < 100; i += 256) sLin[i] = lin_w_l[i];
  if (tid < 10) {
    sLb[tid] = lin_b_l[tid];
    sPb[tid] = post_b_l[tid];
    bnS[tid] = 0.f; bnQ[tid] = 0.f;
  }
  __syncthreads();

  int n = blockIdx.x * 4 + wid;
  if (n < N_NODES) {
    int e_sub = lane / 10;               // 0..6 (lanes 60..63 -> 6, load-inactive)
    int f = lane % 10;
    int t = (lane < 50) ? e_sub : 4;     // compute tower (lanes 50..63 duplicate t=4)
    float wsrc[10];
#pragma unroll
    for (int k = 0; k < 10; k++) wsrc[k] = pre_w_l[(t * 30 + 10 + k) * 10 + f];
    if (lane < 10) sHx[wid][lane] = h[n * 10 + lane];
    float em0 = encm_l[t * 10 + f];
    float em1 = encm_l[50 + t * 10 + f];
    float em2 = encm_l[100 + t * 10 + f];
    float em3 = encm_l[150 + t * 10 + f];
    WAVE_SYNC();
    float xf = sHx[wid][f];
    float base = pre_b_l[t * 10 + f];
#pragma unroll
    for (int k = 0; k < 10; k++) base += sHx[wid][k] * pre_w_l[(t * 30 + k) * 10 + f];

    int rs = rowptr[n], re = rowptr[n + 1];
    int deg = re - rs;
    float sum = 0.f, sq = 0.f, mnv = INFINITY, mxv = -INFINITY;

    for (int cs = rs; cs < re; cs += 60) {
      int cdeg = min(60, re - cs);
      int my_src = 0, my_attr = 0;
      if (lane < cdeg) { my_src = src_s[cs + lane]; my_attr = attr_s[cs + lane]; }
      int nb = (cdeg + 5) / 6;
      // prefetch batch 0
      float hv = 0.f;
      {
        int s0 = __shfl(my_src, e_sub, 64);
        if (e_sub < 6 && e_sub < cdeg) hv = h[s0 * 10 + f];
      }
      for (int b = 0; b < nb; b++) {
        if (e_sub < 6) sE[wid][e_sub][f] = hv;        // stage current batch
        // prefetch next batch while computing current
        int en = (b + 1) * 6 + e_sub;
        int sn = __shfl(my_src, en & 63, 64);
        float hvn = 0.f;
        if (e_sub < 6 && en < cdeg) hvn = h[sn * 10 + f];
        WAVE_SYNC();                                   // sE writes visible wave-wide
        int ecnt = min(6, cdeg - b * 6);
        for (int j = 0; j < ecnt; j++) {
          int aj = __shfl(my_attr, b * 6 + j, 64);
          float m = base + (aj == 0 ? em0 : aj == 1 ? em1 : aj == 2 ? em2 : em3);
          const float4* hp = (const float4*)(&sE[wid][j][0]);
          float4 h0 = hp[0], h1 = hp[1];
          m += h0.x * wsrc[0] + h0.y * wsrc[1] + h0.z * wsrc[2] + h0.w * wsrc[3]
             + h1.x * wsrc[4] + h1.y * wsrc[5] + h1.z * wsrc[6] + h1.w * wsrc[7]
             + sE[wid][j][8] * wsrc[8] + sE[wid][j][9] * wsrc[9];
          sum += m; sq += m * m;
          mnv = fminf(mnv, m); mxv = fmaxf(mxv, m);
        }
        hv = hvn;
        WAVE_SYNC();                                   // reads done before next stage write
      }
    }

    float degf = (float)deg;
    float d = fmaxf(degf, 1.f);
    float inv = 1.f / d;
    float mean = sum * inv;
    float var = sq * inv - mean * mean;
    float stdv = sqrtf(fmaxf(var, 0.f) + 1e-5f);
    if (deg == 0) { mnv = 0.f; mxv = 0.f; }
    float avg_log = avg_log_p[0];
    float log_d = logf(d + 1.f);
    float amp = log_d / avg_log;
    float att = avg_log / log_d;

    // post-NN: distribute the [130 x 2] matmul over 50 (t,f) lanes, 13 k's each
    float vv[13];
    vv[0] = xf;
    vv[1] = mean;       vv[2] = mnv;       vv[3] = mxv;       vv[4] = stdv;
    vv[5] = mean * amp; vv[6] = mnv * amp; vv[7] = mxv * amp; vv[8] = stdv * amp;
    vv[9] = mean * att; vv[10] = mnv * att; vv[11] = mxv * att; vv[12] = stdv * att;
    float p0 = 0.f, p1 = 0.f;
#pragma unroll
    for (int j = 0; j < 13; j++) {
      const float2 w = *(const float2*)&sW[t * 260 + (f + 10 * j) * 2];
      p0 += vv[j] * w.x; p1 += vv[j] * w.y;
    }
    if (lane < 50) *(float2*)&sP[wid][(t * 10 + f) * 2] = make_float2(p0, p1);
    WAVE_SYNC();
    if (lane < 10) {
      int tt = lane >> 1, c = lane & 1;
      float o = sPb[lane];
#pragma unroll
      for (int ff = 0; ff < 10; ff++) o += sP[wid][(tt * 10 + ff) * 2 + c];
      sO[wid][lane] = o;
    }
    WAVE_SYNC();
    if (lane < 10) {
      float r = sLb[lane];
#pragma unroll
      for (int j = 0; j < 10; j++) r += sO[wid][j] * sLin[j * 10 + lane];
      o_buf[n * 10 + lane] = r;
      atomicAdd(&bnS[lane], r);
      atomicAdd(&bnQ[lane], r * r);
    }
  }
  __syncthreads();
  if (tid < 10) {
    atomicAdd(&bn_acc[tid], bnS[tid]);
    atomicAdd(&bn_acc[10 + tid], bnQ[tid]);
  }
}

// ---------------- BN (train-mode) + relu + optional global add pool ----------------
__global__ void k_bnpool(const float* __restrict__ o_buf,
                         const float* __restrict__ bn_acc,
                         const float* __restrict__ gamma, const float* __restrict__ beta,
                         float* __restrict__ h,
                         const int* __restrict__ batch, float* __restrict__ g,
                         int do_pool) {
  int i = blockIdx.x * blockDim.x + threadIdx.x;
  if (i >= N_NODES * 10) return;
  int f = i % 10;
  float mu = bn_acc[f] * (1.f / N_NODES);
  float var = bn_acc[10 + f] * (1.f / N_NODES) - mu * mu;
  float inv = 1.f / sqrtf(fmaxf(var, 0.f) + 1e-5f);
  float o = (o_buf[i] - mu) * inv * gamma[f] + beta[f];
  float r = fmaxf(o, 0.f);
  h[i] = r;
  if (do_pool) atomicAdd(&g[batch[i / 10] * 10 + f], r);
}

// ---------------- mlp2 ----------------
__global__ void k_mlp2(const float* __restrict__ g,
                       const float* __restrict__ w1, const float* __restrict__ b1,
                       const float* __restrict__ w2, const float* __restrict__ b2,
                       float* __restrict__ out) {
  int b = threadIdx.x;
  if (b >= G_GRAPHS) return;
  float gv[10];
#pragma unroll
  for (int k = 0; k < 10; k++) gv[k] = g[b * 10 + k];
  float acc = b2[0];
#pragma unroll
  for (int j = 0; j < 5; j++) {
    float a = b1[j];
#pragma unroll
    for (int k = 0; k < 10; k++) a += gv[k] * w1[k * 5 + j];
    acc += fmaxf(a, 0.f) * w2[j];
  }
  out[b] = acc;
}

extern "C" void kernel_launch(void* const* d_in, const int* in_sizes, int n_in,
                              void* d_out, int out_size, void* d_ws, size_t ws_size,
                              hipStream_t stream) {
  const float* x        = (const float*)d_in[0];
  const float* edge_emb = (const float*)d_in[1];
  const float* m1w1 = (const float*)d_in[2];
  const float* m1b1 = (const float*)d_in[3];
  const float* m1w2 = (const float*)d_in[4];
  const float* m1b2 = (const float*)d_in[5];
  const float* enc_w = (const float*)d_in[6];
  const float* enc_b = (const float*)d_in[7];
  const float* pre_w = (const float*)d_in[8];
  const float* pre_b = (const float*)d_in[9];
  const float* post_w = (const float*)d_in[10];
  const float* post_b = (const float*)d_in[11];
  const float* lin_w = (const float*)d_in[12];
  const float* lin_b = (const float*)d_in[13];
  const float* bn_g = (const float*)d_in[14];
  const float* bn_b = (const float*)d_in[15];
  const float* m2w1 = (const float*)d_in[16];
  const float* m2b1 = (const float*)d_in[17];
  const float* m2w2 = (const float*)d_in[18];
  const float* m2b2 = (const float*)d_in[19];
  const int* edge_index = (const int*)d_in[20];
  const int* edge_attr  = (const int*)d_in[21];
  const int* batch      = (const int*)d_in[22];
  const int* src  = edge_index;
  const int* dstp = edge_index + N_EDGES;

  char* ws = (char*)d_ws;
  size_t off = 0;
  auto alloc = [&](size_t bytes) {
    void* p = ws + off;
    off += (bytes + 255) & ~(size_t)255;
    return p;
  };
  float* h       = (float*)alloc(N_NODES * 10 * sizeof(float));
  float* o_buf   = (float*)alloc(N_NODES * 10 * sizeof(float));
  int*   cnt     = (int*)alloc(N_NODES * sizeof(int));
  int*   fill    = (int*)alloc(N_NODES * sizeof(int));
  int*   rowptr  = (int*)alloc((N_NODES + 1) * sizeof(int));
  int*   src_s   = (int*)alloc(N_EDGES * sizeof(int));
  int*   attr_s  = (int*)alloc(N_EDGES * sizeof(int));
  float* encm    = (float*)alloc(400 * sizeof(float));
  float* avg_log = (float*)alloc(16);
  float* bn_acc  = (float*)alloc(40 * sizeof(float));
  float* g       = (float*)alloc(G_GRAPHS * 10 * sizeof(float));

  k_mlp1<<<(N_NODES + 255) / 256, 256, 0, stream>>>(x, m1w1, m1b1, m1w2, m1b2, h,
                                                    cnt, fill, bn_acc, g);
  k_setup<<<1, 64, 0, stream>>>(edge_emb, enc_w, enc_b, pre_w, encm);
  k_count<<<(N_EDGES + 255) / 256, 256, 0, stream>>>(dstp, cnt);
  k_scan<<<1, 1024, 0, stream>>>(cnt, rowptr, avg_log);
  k_scatter<<<(N_EDGES + 255) / 256, 256, 0, stream>>>(src, dstp, edge_attr, rowptr, fill,
                                                       src_s, attr_s);

  for (int l = 0; l < 2; l++) {
    k_conv<<<(N_NODES + 3) / 4, 256, 0, stream>>>(
        h, pre_w + l * 1500, pre_b + l * 50, post_w + l * 1300, post_b + l * 10,
        lin_w + l * 100, lin_b + l * 10, encm + l * 200,
        rowptr, src_s, attr_s, avg_log, o_buf, bn_acc + l * 20);
    k_bnpool<<<(N_NODES * 10 + 255) / 256, 256, 0, stream>>>(
        o_buf, bn_acc + l * 20, bn_g + l * 10, bn_b + l * 10, h, batch, g, l == 1);
  }
  k_mlp2<<<1, 64, 0, stream>>>(g, m2w1, m2b1, m2w2, m2b2, (float*)d_out);
}

// Round 3
// 481.664 us; speedup vs baseline: 2.1261x; 2.1003x over previous
//
#include <hip/hip_runtime.h>
#include <math.h>

#define N_NODES 50000
#define N_EDGES 800000
#define G_GRAPHS 64
#define CONV_BLOCKS 2048

// ---------------- mlp1 (+ workspace zeroing): h = relu(x@w1+b1)@w2+b2 ----------------
__global__ void k_mlp1(const float* __restrict__ x,
                       const float* __restrict__ w1, const float* __restrict__ b1,
                       const float* __restrict__ w2, const float* __restrict__ b2,
                       float* __restrict__ h,
                       int* __restrict__ cnt, int* __restrict__ fill,
                       float* __restrict__ bn_part, float* __restrict__ g) {
  int n = blockIdx.x * blockDim.x + threadIdx.x;
  if (n < 1280) bn_part[n] = 0.f;          // [2][32][20]
  if (n < G_GRAPHS * 10) g[n] = 0.f;
  if (n >= N_NODES) return;
  cnt[n] = 0;
  fill[n] = 0;
  float xv[10];
#pragma unroll
  for (int k = 0; k < 10; k++) xv[k] = x[n * 10 + k];
  float hid[5];
#pragma unroll
  for (int j = 0; j < 5; j++) {
    float a = b1[j];
#pragma unroll
    for (int k = 0; k < 10; k++) a += xv[k] * w1[k * 5 + j];
    hid[j] = fmaxf(a, 0.f);
  }
#pragma unroll
  for (int f = 0; f < 10; f++) {
    float a = b2[f];
#pragma unroll
    for (int j = 0; j < 5; j++) a += hid[j] * w2[j * 10 + f];
    h[n * 10 + f] = a;
  }
}

// ------- precompute encm[l][a][t][f] = sum_k enc_out[l][a][k]*pre_w[l][t][20+k][f] -------
__global__ void k_setup(const float* __restrict__ edge_emb, // [4][10]
                        const float* __restrict__ enc_w,    // [2][10][10]
                        const float* __restrict__ enc_b,    // [2][10]
                        const float* __restrict__ pre_w,    // [2][5][30][10]
                        float* __restrict__ encm)           // [2][4][5][10]
{
  __shared__ float eo[2][4][10];
  int tid = threadIdx.x;
  for (int i = tid; i < 80; i += 64) {
    int l = i / 40; int a = (i / 10) % 4; int k = i % 10;
    float s = enc_b[l * 10 + k];
    for (int j = 0; j < 10; j++) s += edge_emb[a * 10 + j] * enc_w[(l * 10 + j) * 10 + k];
    eo[l][a][k] = s;
  }
  __syncthreads();
  for (int i = tid; i < 400; i += 64) {
    int l = i / 200; int a = (i / 50) % 4; int t = (i / 10) % 5; int f = i % 10;
    float s = 0.f;
    for (int k = 0; k < 10; k++) s += eo[l][a][k] * pre_w[((l * 5 + t) * 30 + 20 + k) * 10 + f];
    encm[i] = s;
  }
}

// ---------------- degree count ----------------
__global__ void k_count(const int* __restrict__ dst, int* __restrict__ cnt) {
  int e = blockIdx.x * blockDim.x + threadIdx.x;
  if (e < N_EDGES) atomicAdd(&cnt[dst[e]], 1);
}

// ---------------- single-block exclusive scan + avg_log ----------------
__global__ void k_scan(const int* __restrict__ cnt, int* __restrict__ rowptr,
                       float* __restrict__ avg_log) {
  __shared__ int wsum[16];
  __shared__ float wlog[16];
  int tid = threadIdx.x;
  int lane = tid & 63, wid = tid >> 6;
  int carry = 0;
  float logacc = 0.f;
  for (int base = 0; base < N_NODES; base += 1024) {
    int i = base + tid;
    int v = (i < N_NODES) ? cnt[i] : 0;
    if (i < N_NODES) logacc += logf((float)v + 1.0f);
    int x = v;
#pragma unroll
    for (int d = 1; d < 64; d <<= 1) {
      int y = __shfl_up(x, d, 64);
      if (lane >= d) x += y;
    }
    if (lane == 63) wsum[wid] = x;
    __syncthreads();
    if (wid == 0) {
      int t = (lane < 16) ? wsum[lane] : 0;
#pragma unroll
      for (int d = 1; d < 16; d <<= 1) {
        int y = __shfl_up(t, d, 64);
        if (lane >= d) t += y;
      }
      if (lane < 16) wsum[lane] = t;
    }
    __syncthreads();
    int wexcl = (wid > 0) ? wsum[wid - 1] : 0;
    int total = wsum[15];
    if (i < N_NODES) rowptr[i] = carry + wexcl + x - v;
    carry += total;
    __syncthreads();
  }
  if (tid == 0) rowptr[N_NODES] = carry;
  float r = logacc;
#pragma unroll
  for (int d = 32; d >= 1; d >>= 1) r += __shfl_down(r, d, 64);
  if (lane == 0) wlog[wid] = r;
  __syncthreads();
  if (tid == 0) {
    float s = 0.f;
    for (int w = 0; w < 16; w++) s += wlog[w];
    avg_log[0] = s / (float)N_NODES;
  }
}

// ---------------- scatter edges into CSR (packed src|attr<<16) ----------------
__global__ void k_scatter(const int* __restrict__ src, const int* __restrict__ dst,
                          const int* __restrict__ attr,
                          const int* __restrict__ rowptr, int* __restrict__ fill,
                          int* __restrict__ epk) {
  int e = blockIdx.x * blockDim.x + threadIdx.x;
  if (e >= N_EDGES) return;
  int d = dst[e];
  int pos = rowptr[d] + atomicAdd(&fill[d], 1);
  epk[pos] = src[e] | (attr[e] << 16);
}

#define WAVE_SYNC() asm volatile("s_waitcnt lgkmcnt(0)" ::: "memory")

// ---- fused PNA conv: grid-stride waves, register weights, 6-edge-batched gather ----
__global__ __launch_bounds__(256) void k_conv(
    const float* __restrict__ h,
    const float* __restrict__ pre_w_l,   // [5][30][10]
    const float* __restrict__ pre_b_l,   // [5][10]
    const float* __restrict__ post_w_l,  // [5][130][2]
    const float* __restrict__ post_b_l,  // [5][2]
    const float* __restrict__ lin_w_l,   // [10][10]
    const float* __restrict__ lin_b_l,   // [10]
    const float* __restrict__ encm_l,    // [4][5][10]
    const int* __restrict__ rowptr,
    const int* __restrict__ epk,
    const float* __restrict__ avg_log_p,
    float* __restrict__ o_buf,
    float* __restrict__ bn_part)         // [32][20]
{
  __shared__ float sW[1300];
  __shared__ float sLin[100];
  __shared__ float sLb[10];
  __shared__ float sPb[10];
  __shared__ float sE[4][6][12];   // staged h[src] per wave, padded to 12
  __shared__ float sP[4][100];
  __shared__ float sO[4][10];
  __shared__ float sHx[4][7][12];  // prefetched h[n] for up to 7 nodes/wave
  __shared__ float bnS[10], bnQ[10];

  int tid = threadIdx.x;
  int wid = tid >> 6, lane = tid & 63;
  for (int i = tid; i < 1300; i += 256) sW[i] = post_w_l[i];
  for (int i = tid; i < 100; i += 256) sLin[i] = lin_w_l[i];
  if (tid < 10) {
    sLb[tid] = lin_b_l[tid];
    sPb[tid] = post_b_l[tid];
    bnS[tid] = 0.f; bnQ[tid] = 0.f;
  }
  __syncthreads();

  int e_sub = lane / 10;               // 0..6
  int f = lane % 10;
  int t = (lane < 50) ? e_sub : 4;
  // per-wave constant weights in registers
  float wsrc[10], wdst[10];
#pragma unroll
  for (int k = 0; k < 10; k++) {
    wsrc[k] = pre_w_l[(t * 30 + 10 + k) * 10 + f];
    wdst[k] = pre_w_l[(t * 30 + k) * 10 + f];
  }
  float em0 = encm_l[t * 10 + f];
  float em1 = encm_l[50 + t * 10 + f];
  float em2 = encm_l[100 + t * 10 + f];
  float em3 = encm_l[150 + t * 10 + f];
  float preb = pre_b_l[t * 10 + f];
  float avg_log = avg_log_p[0];

  int gw = blockIdx.x * 4 + wid;       // global wave id
  int GW = gridDim.x * 4;
  int nn = (gw < N_NODES) ? ((N_NODES - 1 - gw) / GW + 1) : 0;  // nodes this wave

  // prefetch rowptr pairs for all my nodes (lane-parallel)
  int rp = 0;
  {
    int i = lane >> 1, which = lane & 1;
    if (i < nn) rp = rowptr[gw + i * GW + which];
  }
  // prefetch h[n] for my nodes
  {
    int i = lane / 10, ff = lane % 10;
    if (lane < 60 && i < nn) sHx[wid][i][ff] = h[(gw + i * GW) * 10 + ff];
    if (lane < 10 && nn > 6) sHx[wid][6][lane] = h[(gw + 6 * GW) * 10 + lane];
  }
  WAVE_SYNC();

  float bnSv = 0.f, bnQv = 0.f;

  for (int i = 0; i < nn; i++) {
    int n = gw + i * GW;
    int rs = __shfl(rp, 2 * i, 64);
    int re = __shfl(rp, 2 * i + 1, 64);
    int deg = re - rs;

    float xf = sHx[wid][i][f];
    float base = preb;
#pragma unroll
    for (int k = 0; k < 10; k++) base += sHx[wid][i][k] * wdst[k];

    float sum = 0.f, sq = 0.f, mnv = INFINITY, mxv = -INFINITY;
    for (int cs = rs; cs < re; cs += 60) {
      int cdeg = min(60, re - cs);
      int pk = 0;
      if (lane < cdeg) pk = epk[cs + lane];
      int nb = (cdeg + 5) / 6;
      float hv = 0.f;
      {
        int s0 = __shfl(pk, e_sub, 64) & 0xFFFF;
        if (e_sub < 6 && e_sub < cdeg) hv = h[s0 * 10 + f];
      }
      for (int b = 0; b < nb; b++) {
        if (e_sub < 6) sE[wid][e_sub][f] = hv;
        int en = (b + 1) * 6 + e_sub;
        int pn = __shfl(pk, en & 63, 64);
        float hvn = 0.f;
        if (e_sub < 6 && en < cdeg) hvn = h[(pn & 0xFFFF) * 10 + f];
        WAVE_SYNC();
        int ecnt = min(6, cdeg - b * 6);
        for (int j = 0; j < ecnt; j++) {
          int aj = __shfl(pk, b * 6 + j, 64) >> 16;
          float m = base + (aj == 0 ? em0 : aj == 1 ? em1 : aj == 2 ? em2 : em3);
          const float4* hp = (const float4*)(&sE[wid][j][0]);
          float4 h0 = hp[0], h1 = hp[1];
          m += h0.x * wsrc[0] + h0.y * wsrc[1] + h0.z * wsrc[2] + h0.w * wsrc[3]
             + h1.x * wsrc[4] + h1.y * wsrc[5] + h1.z * wsrc[6] + h1.w * wsrc[7]
             + sE[wid][j][8] * wsrc[8] + sE[wid][j][9] * wsrc[9];
          sum += m; sq += m * m;
          mnv = fminf(mnv, m); mxv = fmaxf(mxv, m);
        }
        hv = hvn;
        WAVE_SYNC();
      }
    }

    float degf = (float)deg;
    float d = fmaxf(degf, 1.f);
    float inv = 1.f / d;
    float mean = sum * inv;
    float var = sq * inv - mean * mean;
    float stdv = sqrtf(fmaxf(var, 0.f) + 1e-5f);
    if (deg == 0) { mnv = 0.f; mxv = 0.f; }
    float log_d = logf(d + 1.f);
    float amp = log_d / avg_log;
    float att = avg_log / log_d;

    float vv[13];
    vv[0] = xf;
    vv[1] = mean;       vv[2] = mnv;        vv[3] = mxv;        vv[4] = stdv;
    vv[5] = mean * amp; vv[6] = mnv * amp;  vv[7] = mxv * amp;  vv[8] = stdv * amp;
    vv[9] = mean * att; vv[10] = mnv * att; vv[11] = mxv * att; vv[12] = stdv * att;
    float p0 = 0.f, p1 = 0.f;
#pragma unroll
    for (int j = 0; j < 13; j++) {
      const float2 w = *(const float2*)&sW[t * 260 + (f + 10 * j) * 2];
      p0 += vv[j] * w.x; p1 += vv[j] * w.y;
    }
    if (lane < 50) *(float2*)&sP[wid][(t * 10 + f) * 2] = make_float2(p0, p1);
    WAVE_SYNC();
    if (lane < 10) {
      int tt = lane >> 1, c = lane & 1;
      float o = sPb[lane];
#pragma unroll
      for (int ff = 0; ff < 10; ff++) o += sP[wid][(tt * 10 + ff) * 2 + c];
      sO[wid][lane] = o;
    }
    WAVE_SYNC();
    if (lane < 10) {
      float r = sLb[lane];
#pragma unroll
      for (int j = 0; j < 10; j++) r += sO[wid][j] * sLin[j * 10 + lane];
      o_buf[n * 10 + lane] = r;
      bnSv += r; bnQv += r * r;
    }
    WAVE_SYNC();  // sO/sP reads done before next node reuses them
  }

  if (lane < 10) {
    atomicAdd(&bnS[lane], bnSv);
    atomicAdd(&bnQ[lane], bnQv);
  }
  __syncthreads();
  if (tid < 20) {
    float v = (tid < 10) ? bnS[tid] : bnQ[tid - 10];
    atomicAdd(&bn_part[(blockIdx.x & 31) * 20 + tid], v);
  }
}

// ---------------- BN (train-mode, from 32 partials) + relu + optional pool ----------------
__global__ void k_bnpool(const float* __restrict__ o_buf,
                         const float* __restrict__ bn_part,  // [32][20]
                         const float* __restrict__ gamma, const float* __restrict__ beta,
                         float* __restrict__ h,
                         const int* __restrict__ batch, float* __restrict__ g,
                         int do_pool) {
  __shared__ float sS[20];
  __shared__ float sMu[10], sInv[10];
  int tid = threadIdx.x;
  if (tid < 20) {
    float s = 0.f;
    for (int j = 0; j < 32; j++) s += bn_part[j * 20 + tid];
    sS[tid] = s;
  }
  __syncthreads();
  if (tid < 10) {
    float mu = sS[tid] * (1.f / N_NODES);
    float var = sS[10 + tid] * (1.f / N_NODES) - mu * mu;
    sMu[tid] = mu;
    sInv[tid] = 1.f / sqrtf(fmaxf(var, 0.f) + 1e-5f);
  }
  __syncthreads();
  int i = blockIdx.x * blockDim.x + tid;
  if (i >= N_NODES * 10) return;
  int f = i % 10;
  float o = (o_buf[i] - sMu[f]) * sInv[f] * gamma[f] + beta[f];
  float r = fmaxf(o, 0.f);
  h[i] = r;
  if (do_pool) atomicAdd(&g[batch[i / 10] * 10 + f], r);
}

// ---------------- mlp2 ----------------
__global__ void k_mlp2(const float* __restrict__ g,
                       const float* __restrict__ w1, const float* __restrict__ b1,
                       const float* __restrict__ w2, const float* __restrict__ b2,
                       float* __restrict__ out) {
  int b = threadIdx.x;
  if (b >= G_GRAPHS) return;
  float gv[10];
#pragma unroll
  for (int k = 0; k < 10; k++) gv[k] = g[b * 10 + k];
  float acc = b2[0];
#pragma unroll
  for (int j = 0; j < 5; j++) {
    float a = b1[j];
#pragma unroll
    for (int k = 0; k < 10; k++) a += gv[k] * w1[k * 5 + j];
    acc += fmaxf(a, 0.f) * w2[j];
  }
  out[b] = acc;
}

extern "C" void kernel_launch(void* const* d_in, const int* in_sizes, int n_in,
                              void* d_out, int out_size, void* d_ws, size_t ws_size,
                              hipStream_t stream) {
  const float* x        = (const float*)d_in[0];
  const float* edge_emb = (const float*)d_in[1];
  const float* m1w1 = (const float*)d_in[2];
  const float* m1b1 = (const float*)d_in[3];
  const float* m1w2 = (const float*)d_in[4];
  const float* m1b2 = (const float*)d_in[5];
  const float* enc_w = (const float*)d_in[6];
  const float* enc_b = (const float*)d_in[7];
  const float* pre_w = (const float*)d_in[8];
  const float* pre_b = (const float*)d_in[9];
  const float* post_w = (const float*)d_in[10];
  const float* post_b = (const float*)d_in[11];
  const float* lin_w = (const float*)d_in[12];
  const float* lin_b = (const float*)d_in[13];
  const float* bn_g = (const float*)d_in[14];
  const float* bn_b = (const float*)d_in[15];
  const float* m2w1 = (const float*)d_in[16];
  const float* m2b1 = (const float*)d_in[17];
  const float* m2w2 = (const float*)d_in[18];
  const float* m2b2 = (const float*)d_in[19];
  const int* edge_index = (const int*)d_in[20];
  const int* edge_attr  = (const int*)d_in[21];
  const int* batch      = (const int*)d_in[22];
  const int* src  = edge_index;
  const int* dstp = edge_index + N_EDGES;

  char* ws = (char*)d_ws;
  size_t off = 0;
  auto alloc = [&](size_t bytes) {
    void* p = ws + off;
    off += (bytes + 255) & ~(size_t)255;
    return p;
  };
  float* h       = (float*)alloc(N_NODES * 10 * sizeof(float));
  float* o_buf   = (float*)alloc(N_NODES * 10 * sizeof(float));
  int*   cnt     = (int*)alloc(N_NODES * sizeof(int));
  int*   fill    = (int*)alloc(N_NODES * sizeof(int));
  int*   rowptr  = (int*)alloc((N_NODES + 1) * sizeof(int));
  int*   epk     = (int*)alloc(N_EDGES * sizeof(int));
  float* encm    = (float*)alloc(400 * sizeof(float));
  float* avg_log = (float*)alloc(16);
  float* bn_part = (float*)alloc(2 * 32 * 20 * sizeof(float));
  float* g       = (float*)alloc(G_GRAPHS * 10 * sizeof(float));

  k_mlp1<<<(N_NODES + 255) / 256, 256, 0, stream>>>(x, m1w1, m1b1, m1w2, m1b2, h,
                                                    cnt, fill, bn_part, g);
  k_setup<<<1, 64, 0, stream>>>(edge_emb, enc_w, enc_b, pre_w, encm);
  k_count<<<(N_EDGES + 255) / 256, 256, 0, stream>>>(dstp, cnt);
  k_scan<<<1, 1024, 0, stream>>>(cnt, rowptr, avg_log);
  k_scatter<<<(N_EDGES + 255) / 256, 256, 0, stream>>>(src, dstp, edge_attr, rowptr, fill,
                                                       epk);

  for (int l = 0; l < 2; l++) {
    k_conv<<<CONV_BLOCKS, 256, 0, stream>>>(
        h, pre_w + l * 1500, pre_b + l * 50, post_w + l * 1300, post_b + l * 10,
        lin_w + l * 100, lin_b + l * 10, encm + l * 200,
        rowptr, epk, avg_log, o_buf, bn_part + l * 640);
    k_bnpool<<<(N_NODES * 10 + 255) / 256, 256, 0, stream>>>(
        o_buf, bn_part + l * 640, bn_g + l * 10, bn_b + l * 10, h, batch, g, l == 1);
  }
  k_mlp2<<<1, 64, 0, stream>>>(g, m2w1, m2b1, m2w2, m2b2, (float*)d_out);
}

// Round 4
// 431.884 us; speedup vs baseline: 2.3712x; 1.1153x over previous
//
#include <hip/hip_runtime.h>
#include <math.h>

#define N_NODES 50000
#define N_EDGES 800000
#define G_GRAPHS 64
#define CONV_BLOCKS 2048

// ---------------- mlp1 (+ workspace zeroing): h = relu(x@w1+b1)@w2+b2 ----------------
__global__ void k_mlp1(const float* __restrict__ x,
                       const float* __restrict__ w1, const float* __restrict__ b1,
                       const float* __restrict__ w2, const float* __restrict__ b2,
                       float* __restrict__ h,
                       int* __restrict__ cnt, int* __restrict__ fill,
                       float* __restrict__ bn_part, float* __restrict__ g) {
  int n = blockIdx.x * blockDim.x + threadIdx.x;
  if (n < 1280) bn_part[n] = 0.f;          // [2][32][20]
  if (n < G_GRAPHS * 10) g[n] = 0.f;
  if (n >= N_NODES) return;
  cnt[n] = 0;
  fill[n] = 0;
  float xv[10];
#pragma unroll
  for (int k = 0; k < 10; k++) xv[k] = x[n * 10 + k];
  float hid[5];
#pragma unroll
  for (int j = 0; j < 5; j++) {
    float a = b1[j];
#pragma unroll
    for (int k = 0; k < 10; k++) a += xv[k] * w1[k * 5 + j];
    hid[j] = fmaxf(a, 0.f);
  }
#pragma unroll
  for (int f = 0; f < 10; f++) {
    float a = b2[f];
#pragma unroll
    for (int j = 0; j < 5; j++) a += hid[j] * w2[j * 10 + f];
    h[n * 10 + f] = a;
  }
}

// ------- precompute encm[l][a][t][f] = sum_k enc_out[l][a][k]*pre_w[l][t][20+k][f] -------
__global__ void k_setup(const float* __restrict__ edge_emb, // [4][10]
                        const float* __restrict__ enc_w,    // [2][10][10]
                        const float* __restrict__ enc_b,    // [2][10]
                        const float* __restrict__ pre_w,    // [2][5][30][10]
                        float* __restrict__ encm)           // [2][4][5][10]
{
  __shared__ float eo[2][4][10];
  int tid = threadIdx.x;
  for (int i = tid; i < 80; i += 64) {
    int l = i / 40; int a = (i / 10) % 4; int k = i % 10;
    float s = enc_b[l * 10 + k];
    for (int j = 0; j < 10; j++) s += edge_emb[a * 10 + j] * enc_w[(l * 10 + j) * 10 + k];
    eo[l][a][k] = s;
  }
  __syncthreads();
  for (int i = tid; i < 400; i += 64) {
    int l = i / 200; int a = (i / 50) % 4; int t = (i / 10) % 5; int f = i % 10;
    float s = 0.f;
    for (int k = 0; k < 10; k++) s += eo[l][a][k] * pre_w[((l * 5 + t) * 30 + 20 + k) * 10 + f];
    encm[i] = s;
  }
}

// ---------------- degree count ----------------
__global__ void k_count(const int* __restrict__ dst, int* __restrict__ cnt) {
  int e = blockIdx.x * blockDim.x + threadIdx.x;
  if (e < N_EDGES) atomicAdd(&cnt[dst[e]], 1);
}

// ---------------- single-block exclusive scan + avg_log (int4, log-of-product) ----------------
__global__ void k_scan(const int* __restrict__ cnt, int* __restrict__ rowptr,
                       float* __restrict__ avg_log) {
  __shared__ int wsum[16];
  __shared__ float wlog[16];
  int tid = threadIdx.x;
  int lane = tid & 63, wid = tid >> 6;
  int carry = 0;
  float logacc = 0.f;
  // N_NODES divisible by 4: all int4 loads with i0 < N are fully valid
  for (int base = 0; base < N_NODES; base += 4096) {
    int i0 = base + tid * 4;
    int4 v = make_int4(0, 0, 0, 0);
    if (i0 < N_NODES) v = *(const int4*)&cnt[i0];
    float p = (float)(v.x + 1) * (float)(v.y + 1) * (float)(v.z + 1) * (float)(v.w + 1);
    logacc += __logf(p);
    int t4 = v.x + v.y + v.z + v.w;
    int x = t4;
#pragma unroll
    for (int d = 1; d < 64; d <<= 1) {
      int y = __shfl_up(x, d, 64);
      if (lane >= d) x += y;
    }
    if (lane == 63) wsum[wid] = x;
    __syncthreads();
    if (wid == 0) {
      int t = (lane < 16) ? wsum[lane] : 0;
#pragma unroll
      for (int d = 1; d < 16; d <<= 1) {
        int y = __shfl_up(t, d, 64);
        if (lane >= d) t += y;
      }
      if (lane < 16) wsum[lane] = t;
    }
    __syncthreads();
    int wexcl = (wid > 0) ? wsum[wid - 1] : 0;
    int total = wsum[15];
    if (i0 < N_NODES) {
      int e0 = carry + wexcl + x - t4;
      int4 r = make_int4(e0, e0 + v.x, e0 + v.x + v.y, e0 + v.x + v.y + v.z);
      *(int4*)&rowptr[i0] = r;
    }
    carry += total;
    __syncthreads();
  }
  if (tid == 0) rowptr[N_NODES] = carry;
  float r = logacc;
#pragma unroll
  for (int d = 32; d >= 1; d >>= 1) r += __shfl_down(r, d, 64);
  if (lane == 0) wlog[wid] = r;
  __syncthreads();
  if (tid == 0) {
    float s = 0.f;
    for (int w = 0; w < 16; w++) s += wlog[w];
    avg_log[0] = s / (float)N_NODES;
  }
}

// ---------------- scatter edges into CSR (packed src|attr<<16) ----------------
__global__ void k_scatter(const int* __restrict__ src, const int* __restrict__ dst,
                          const int* __restrict__ attr,
                          const int* __restrict__ rowptr, int* __restrict__ fill,
                          int* __restrict__ epk) {
  int e = blockIdx.x * blockDim.x + threadIdx.x;
  if (e >= N_EDGES) return;
  int d = dst[e];
  int pos = rowptr[d] + atomicAdd(&fill[d], 1);
  epk[pos] = src[e] | (attr[e] << 16);
}

#define WAVE_SYNC() asm volatile("s_waitcnt lgkmcnt(0)" ::: "memory")
#define RFL(v) __builtin_amdgcn_readfirstlane(v)

// ---- fused PNA conv: grid-stride waves, onehot-fused em, unrolled 6-edge batches ----
__global__ __launch_bounds__(256) void k_conv(
    const float* __restrict__ h,
    const float* __restrict__ pre_w_l,   // [5][30][10]
    const float* __restrict__ pre_b_l,   // [5][10]
    const float* __restrict__ post_w_l,  // [5][130][2]
    const float* __restrict__ post_b_l,  // [5][2]
    const float* __restrict__ lin_w_l,   // [10][10]
    const float* __restrict__ lin_b_l,   // [10]
    const float* __restrict__ encm_l,    // [4][5][10]
    const int* __restrict__ rowptr,
    const int* __restrict__ epk,
    const float* __restrict__ avg_log_p,
    float* __restrict__ o_buf,
    float* __restrict__ bn_part)         // [32][20]
{
  __shared__ float sW[1300];
  __shared__ float sLin[100];
  __shared__ float sLb[10];
  __shared__ float sPb[10];
  __shared__ float sE[4][6][16];   // 6 staged edges: [h_src(10), onehot(4), pad(2)]
  __shared__ float sP[4][100];
  __shared__ float sO[4][10];
  __shared__ float sHx[4][7][12];  // prefetched h[n] for up to 7 nodes/wave
  __shared__ float bnS[10], bnQ[10];

  int tid = threadIdx.x;
  int wid = tid >> 6, lane = tid & 63;
  for (int i = tid; i < 1300; i += 256) sW[i] = post_w_l[i];
  for (int i = tid; i < 100; i += 256) sLin[i] = lin_w_l[i];
  if (tid < 10) {
    sLb[tid] = lin_b_l[tid];
    sPb[tid] = post_b_l[tid];
    bnS[tid] = 0.f; bnQ[tid] = 0.f;
  }
  __syncthreads();

  int e_sub = lane / 10;               // 0..6
  int f = lane % 10;
  int t = (lane < 50) ? e_sub : 4;
  // per-wave constant weights in registers: w14 = [wsrc(10), em0..3]
  float w14[14], wdst[10];
#pragma unroll
  for (int k = 0; k < 10; k++) {
    w14[k] = pre_w_l[(t * 30 + 10 + k) * 10 + f];
    wdst[k] = pre_w_l[(t * 30 + k) * 10 + f];
  }
#pragma unroll
  for (int a = 0; a < 4; a++) w14[10 + a] = encm_l[a * 50 + t * 10 + f];
  float preb = pre_b_l[t * 10 + f];
  float avg_log = avg_log_p[0];

  int gw = blockIdx.x * 4 + wid;       // global wave id
  int GW = gridDim.x * 4;
  int nn = (gw < N_NODES) ? ((N_NODES - 1 - gw) / GW + 1) : 0;

  // prefetch rowptr pairs for all my nodes (lane-parallel)
  int rp = 0;
  {
    int i = lane >> 1, which = lane & 1;
    if (i < nn) rp = rowptr[gw + i * GW + which];
  }
  // prefetch h[n] for my nodes
  {
    int i = lane / 10, ff = lane % 10;
    if (lane < 60 && i < nn) sHx[wid][i][ff] = h[(gw + i * GW) * 10 + ff];
    if (lane < 10 && nn > 6) sHx[wid][6][lane] = h[(gw + 6 * GW) * 10 + lane];
  }
  WAVE_SYNC();

  float bnSv = 0.f, bnQv = 0.f;

  for (int i = 0; i < nn; i++) {
    int n = gw + i * GW;
    int rs = RFL(__builtin_amdgcn_readlane(rp, 2 * i));      // scalar bounds
    int re = RFL(__builtin_amdgcn_readlane(rp, 2 * i + 1));
    int deg = re - rs;

    float xf = sHx[wid][i][f];
    float base = preb;
#pragma unroll
    for (int k = 0; k < 10; k++) base += sHx[wid][i][k] * wdst[k];

    float sum = 0.f, sq = 0.f, mnv = INFINITY, mxv = -INFINITY;
    for (int cs = rs; cs < re; cs += 60) {
      int cdeg = min(60, re - cs);       // scalar
      int pk = 0;
      if (lane < cdeg) pk = epk[cs + lane];
      int nb = (cdeg + 5) / 6;
      // prefetch batch 0 for staging lanes
      int spk = __shfl(pk, e_sub, 64);
      bool sval = (e_sub < 6) && (e_sub < cdeg);
      float hv = sval ? h[(spk & 0xFFFF) * 10 + f] : 0.f;
      float oh = (sval && f < 4 && ((spk >> 16) == f)) ? 1.f : 0.f;
      for (int b = 0; b < nb; b++) {
        if (e_sub < 6) {
          sE[wid][e_sub][f] = hv;
          if (f < 4) sE[wid][e_sub][10 + f] = oh;
        }
        int en = (b + 1) * 6 + e_sub;
        int pn = __shfl(pk, en & 63, 64);
        bool nval = (e_sub < 6) && (en < cdeg);
        float hvn = nval ? h[(pn & 0xFFFF) * 10 + f] : 0.f;
        float ohn = (nval && f < 4 && ((pn >> 16) == f)) ? 1.f : 0.f;
        WAVE_SYNC();
        int ecnt = min(6, cdeg - b * 6);  // scalar
        if (ecnt == 6) {
#pragma unroll
          for (int j = 0; j < 6; j++) {
            const float4* ep = (const float4*)&sE[wid][j][0];
            float4 a0 = ep[0], a1 = ep[1], a2 = ep[2];
            float2 a3 = *(const float2*)&sE[wid][j][12];
            float m = base
              + a0.x * w14[0] + a0.y * w14[1] + a0.z * w14[2] + a0.w * w14[3]
              + a1.x * w14[4] + a1.y * w14[5] + a1.z * w14[6] + a1.w * w14[7]
              + a2.x * w14[8] + a2.y * w14[9] + a2.z * w14[10] + a2.w * w14[11]
              + a3.x * w14[12] + a3.y * w14[13];
            sum += m; sq = fmaf(m, m, sq);
            mnv = fminf(mnv, m); mxv = fmaxf(mxv, m);
          }
        } else {
#pragma unroll
          for (int j = 0; j < 6; j++) {
            if (j < ecnt) {
              const float4* ep = (const float4*)&sE[wid][j][0];
              float4 a0 = ep[0], a1 = ep[1], a2 = ep[2];
              float2 a3 = *(const float2*)&sE[wid][j][12];
              float m = base
                + a0.x * w14[0] + a0.y * w14[1] + a0.z * w14[2] + a0.w * w14[3]
                + a1.x * w14[4] + a1.y * w14[5] + a1.z * w14[6] + a1.w * w14[7]
                + a2.x * w14[8] + a2.y * w14[9] + a2.z * w14[10] + a2.w * w14[11]
                + a3.x * w14[12] + a3.y * w14[13];
              sum += m; sq = fmaf(m, m, sq);
              mnv = fminf(mnv, m); mxv = fmaxf(mxv, m);
            }
          }
        }
        hv = hvn; oh = ohn;
        WAVE_SYNC();
      }
    }

    float degf = (float)deg;
    float d = fmaxf(degf, 1.f);
    float inv = 1.f / d;
    float mean = sum * inv;
    float var = sq * inv - mean * mean;
    float stdv = sqrtf(fmaxf(var, 0.f) + 1e-5f);
    if (deg == 0) { mnv = 0.f; mxv = 0.f; }
    float log_d = logf(d + 1.f);
    float amp = log_d / avg_log;
    float att = avg_log / log_d;

    float vv[13];
    vv[0] = xf;
    vv[1] = mean;       vv[2] = mnv;        vv[3] = mxv;        vv[4] = stdv;
    vv[5] = mean * amp; vv[6] = mnv * amp;  vv[7] = mxv * amp;  vv[8] = stdv * amp;
    vv[9] = mean * att; vv[10] = mnv * att; vv[11] = mxv * att; vv[12] = stdv * att;
    float p0 = 0.f, p1 = 0.f;
#pragma unroll
    for (int j = 0; j < 13; j++) {
      const float2 w = *(const float2*)&sW[t * 260 + (f + 10 * j) * 2];
      p0 += vv[j] * w.x; p1 += vv[j] * w.y;
    }
    if (lane < 50) *(float2*)&sP[wid][(t * 10 + f) * 2] = make_float2(p0, p1);
    WAVE_SYNC();
    if (lane < 10) {
      int tt = lane >> 1, c = lane & 1;
      float o = sPb[lane];
#pragma unroll
      for (int ff = 0; ff < 10; ff++) o += sP[wid][(tt * 10 + ff) * 2 + c];
      sO[wid][lane] = o;
    }
    WAVE_SYNC();
    if (lane < 10) {
      float r = sLb[lane];
#pragma unroll
      for (int j = 0; j < 10; j++) r += sO[wid][j] * sLin[j * 10 + lane];
      o_buf[n * 10 + lane] = r;
      bnSv += r; bnQv += r * r;
    }
    WAVE_SYNC();  // sO/sP reads done before next node reuses them
  }

  if (lane < 10) {
    atomicAdd(&bnS[lane], bnSv);
    atomicAdd(&bnQ[lane], bnQv);
  }
  __syncthreads();
  if (tid < 20) {
    float v = (tid < 10) ? bnS[tid] : bnQ[tid - 10];
    atomicAdd(&bn_part[(blockIdx.x & 31) * 20 + tid], v);
  }
}

// ---------------- BN (train-mode, from 32 partials) + relu + optional pool ----------------
__global__ void k_bnpool(const float* __restrict__ o_buf,
                         const float* __restrict__ bn_part,  // [32][20]
                         const float* __restrict__ gamma, const float* __restrict__ beta,
                         float* __restrict__ h,
                         const int* __restrict__ batch, float* __restrict__ g,
                         int do_pool) {
  __shared__ float sS[20];
  __shared__ float sMu[10], sInv[10];
  int tid = threadIdx.x;
  if (tid < 20) {
    float s = 0.f;
    for (int j = 0; j < 32; j++) s += bn_part[j * 20 + tid];
    sS[tid] = s;
  }
  __syncthreads();
  if (tid < 10) {
    float mu = sS[tid] * (1.f / N_NODES);
    float var = sS[10 + tid] * (1.f / N_NODES) - mu * mu;
    sMu[tid] = mu;
    sInv[tid] = 1.f / sqrtf(fmaxf(var, 0.f) + 1e-5f);
  }
  __syncthreads();
  int i = blockIdx.x * blockDim.x + tid;
  if (i >= N_NODES * 10) return;
  int f = i % 10;
  float o = (o_buf[i] - sMu[f]) * sInv[f] * gamma[f] + beta[f];
  float r = fmaxf(o, 0.f);
  h[i] = r;
  if (do_pool) atomicAdd(&g[batch[i / 10] * 10 + f], r);
}

// ---------------- mlp2 ----------------
__global__ void k_mlp2(const float* __restrict__ g,
                       const float* __restrict__ w1, const float* __restrict__ b1,
                       const float* __restrict__ w2, const float* __restrict__ b2,
                       float* __restrict__ out) {
  int b = threadIdx.x;
  if (b >= G_GRAPHS) return;
  float gv[10];
#pragma unroll
  for (int k = 0; k < 10; k++) gv[k] = g[b * 10 + k];
  float acc = b2[0];
#pragma unroll
  for (int j = 0; j < 5; j++) {
    float a = b1[j];
#pragma unroll
    for (int k = 0; k < 10; k++) a += gv[k] * w1[k * 5 + j];
    acc += fmaxf(a, 0.f) * w2[j];
  }
  out[b] = acc;
}

extern "C" void kernel_launch(void* const* d_in, const int* in_sizes, int n_in,
                              void* d_out, int out_size, void* d_ws, size_t ws_size,
                              hipStream_t stream) {
  const float* x        = (const float*)d_in[0];
  const float* edge_emb = (const float*)d_in[1];
  const float* m1w1 = (const float*)d_in[2];
  const float* m1b1 = (const float*)d_in[3];
  const float* m1w2 = (const float*)d_in[4];
  const float* m1b2 = (const float*)d_in[5];
  const float* enc_w = (const float*)d_in[6];
  const float* enc_b = (const float*)d_in[7];
  const float* pre_w = (const float*)d_in[8];
  const float* pre_b = (const float*)d_in[9];
  const float* post_w = (const float*)d_in[10];
  const float* post_b = (const float*)d_in[11];
  const float* lin_w = (const float*)d_in[12];
  const float* lin_b = (const float*)d_in[13];
  const float* bn_g = (const float*)d_in[14];
  const float* bn_b = (const float*)d_in[15];
  const float* m2w1 = (const float*)d_in[16];
  const float* m2b1 = (const float*)d_in[17];
  const float* m2w2 = (const float*)d_in[18];
  const float* m2b2 = (const float*)d_in[19];
  const int* edge_index = (const int*)d_in[20];
  const int* edge_attr  = (const int*)d_in[21];
  const int* batch      = (const int*)d_in[22];
  const int* src  = edge_index;
  const int* dstp = edge_index + N_EDGES;

  char* ws = (char*)d_ws;
  size_t off = 0;
  auto alloc = [&](size_t bytes) {
    void* p = ws + off;
    off += (bytes + 255) & ~(size_t)255;
    return p;
  };
  float* h       = (float*)alloc(N_NODES * 10 * sizeof(float));
  float* o_buf   = (float*)alloc(N_NODES * 10 * sizeof(float));
  int*   cnt     = (int*)alloc(N_NODES * sizeof(int));
  int*   fill    = (int*)alloc(N_NODES * sizeof(int));
  int*   rowptr  = (int*)alloc((N_NODES + 1) * sizeof(int));
  int*   epk     = (int*)alloc(N_EDGES * sizeof(int));
  float* encm    = (float*)alloc(400 * sizeof(float));
  float* avg_log = (float*)alloc(16);
  float* bn_part = (float*)alloc(2 * 32 * 20 * sizeof(float));
  float* g       = (float*)alloc(G_GRAPHS * 10 * sizeof(float));

  k_mlp1<<<(N_NODES + 255) / 256, 256, 0, stream>>>(x, m1w1, m1b1, m1w2, m1b2, h,
                                                    cnt, fill, bn_part, g);
  k_setup<<<1, 64, 0, stream>>>(edge_emb, enc_w, enc_b, pre_w, encm);
  k_count<<<(N_EDGES + 255) / 256, 256, 0, stream>>>(dstp, cnt);
  k_scan<<<1, 1024, 0, stream>>>(cnt, rowptr, avg_log);
  k_scatter<<<(N_EDGES + 255) / 256, 256, 0, stream>>>(src, dstp, edge_attr, rowptr, fill,
                                                       epk);

  for (int l = 0; l < 2; l++) {
    k_conv<<<CONV_BLOCKS, 256, 0, stream>>>(
        h, pre_w + l * 1500, pre_b + l * 50, post_w + l * 1300, post_b + l * 10,
        lin_w + l * 100, lin_b + l * 10, encm + l * 200,
        rowptr, epk, avg_log, o_buf, bn_part + l * 640);
    k_bnpool<<<(N_NODES * 10 + 255) / 256, 256, 0, stream>>>(
        o_buf, bn_part + l * 640, bn_g + l * 10, bn_b + l * 10, h, batch, g, l == 1);
  }
  k_mlp2<<<1, 64, 0, stream>>>(g, m2w1, m2b1, m2w2, m2b2, (float*)d_out);
}